// Round 7
// baseline (1014.261 us; speedup 1.0000x reference)
//
#include <hip/hip_runtime.h>
#include <hip/hip_bf16.h>

// B=2, L=4096, D=768, H=12, HS=64, SCALE=0.125. Inputs/outputs fp32; bf16 MFMA inside.
#define LQ 4096
#define DQ 768
#define NH 12
#define NB 2

typedef __attribute__((ext_vector_type(8))) short short8;
typedef __attribute__((ext_vector_type(2))) unsigned uint2v;
typedef __attribute__((ext_vector_type(4))) unsigned uint4v;
typedef __attribute__((ext_vector_type(4))) float f32x4;

__device__ __forceinline__ short f2bf(float f) {
    union { float f; unsigned u; } v; v.f = f;
    unsigned r = v.u + 0x7FFFu + ((v.u >> 16) & 1u);   // RNE
    return (short)(r >> 16);
}

__device__ __forceinline__ unsigned pk2(float a, float b) {
    float2 t; t.x = a; t.y = b;
    __hip_bfloat162 h = __float22bfloat162_rn(t);
    unsigned u; __builtin_memcpy(&u, &h, 4);
    return u;
}

__device__ __forceinline__ f32x4 mfma16(short8 a, short8 b, f32x4 c) {
    return __builtin_amdgcn_mfma_f32_16x16x32_bf16(a, b, c, 0, 0, 0);
}

// async 16B global->LDS DMA (dest = wave-uniform base + lane*16)
__device__ __forceinline__ void gld16(const short* g, short* l) {
    __builtin_amdgcn_global_load_lds(
        (const __attribute__((address_space(1))) unsigned int*)(g),
        (__attribute__((address_space(3))) unsigned int*)(l), 16, 0, 0);
}

// sqrt(0.125 * log2(e)): Qf pre-scaled so S^T = (Q')(Q')^T is directly in exp2 domain
#define SQRT_C 0.424660891f

// fp32 -> bf16 bulk convert, n multiple of 1024
__global__ __launch_bounds__(256) void cvtw(const float* __restrict__ a,
                                            short* __restrict__ o) {
    int i = blockIdx.x * 256 + threadIdx.x;
    float4 v = ((const float4*)a)[i];
    *(uint2v*)&o[i * 4] = (uint2v){pk2(v.x, v.y), pk2(v.z, v.w)};
}

// Fragment-major layouts (per bh, per 64-key tile = 4096 shorts, 8 chunks of 512):
//  Qf chunk(t4,s): lane L holds Q[key=16*t4+(L&15)][d=32*s+8*(L>>4)+j]  (SCALED by SQRT_C)
//  Vf chunk(t2,ks): lane L holds Q[key=32*ks+8*(L>>4)+j][d=16*t2+(L&15)] (unscaled)
// Chunk layout is LINEAR in key: 32-key sub-tile kb reads Qf at kb*2048 + (t4*2+s)*512.

// C[M,N] = A[M,K] @ W[N,K]^T, M=8192, N=768, K=768.
// ROUND-7 THEORY OF THE GEMM PLATEAU: rounds 2-4 had 3 blocks/CU but thin 64x32 wave
// tiles (overhead-bound); rounds 5-6 had fat wave tiles but 1 block/CU -- every per-kt
// barrier (vmcnt(0) drain) stalls the whole CU with no other block to hide it (the m97
// stall; m97 itself ran 3 blocks/CU). Fat tiles + multi-block residency were never
// combined. NOW: BM=64, BN=192, BK=64, 512 threads = 8 waves (2m x 4n) of 32x48 out
// (acc[2][3], 12 MFMA : 10 ds_read/kt), grid 512 (128 mt x 4 nt) = 2 blocks/CU
// (launch_bounds(512,4), LDS 64KB so 2x64 fits 160KB). W pre-cvt to bf16 (DMA-staged
// both modes); MODE 1 stages A from fp32 x with in-reg cvt (round-6 pattern).
// G21 XOR swizzle throughout (source chunk k ^ (row&7), linear LDS write, reads
// un-swizzle). MODE 0: C fp32 row-major. MODE 1: per-head F slabs (4096 shorts,
// BM=64 = exactly one 64-key fragment tile), scatter math = verified round-5/6
// formulas with the (kl>>6) term dropped (always 0 at BM=64).
template <int MODE>
__global__ __launch_bounds__(512, 4) void gemm_nt(const short* __restrict__ Abf,
                                                  const float* __restrict__ Axf,
                                                  const short* __restrict__ Wb,
                                                  void* __restrict__ Cp,
                                                  short* __restrict__ Vf) {
    // carve: As[2][4096] = smem[0..8192), Bs[2][12288] = smem[8192..32768)
    __shared__ __attribute__((aligned(16))) short smem[32768];   // 64 KB
    const int t = threadIdx.x;
    const int lane = t & 63, w = t >> 6;                 // 8 waves
    const int lr = lane & 15, qd = lane >> 4;
    const int wm = (w >> 2) * 32, wn = (w & 3) * 48;     // wave tile 32m x 48n
    const int lin = blockIdx.x;
    const int xcd = lin & 7, jj = lin >> 3;              // 512 blocks, 8 XCDs
    const int nt = jj & 3, mt = (jj >> 2) * 8 + xcd;     // 4 n-tiles x 128 m-tiles
    const int m0 = mt * 64, n0 = nt * 192;

    // kt-invariant source offsets (XOR-swizzled chunk within each 8-chunk row)
    int aoff;
    if (MODE == 0) {
        int c = w * 64 + lane;                           // A 16B-unit id 0..511 (DMA)
        int row = c >> 3, k = (c & 7) ^ (row & 7);
        aoff = (m0 + row) * DQ + k * 8;
    } else {
        int row = t >> 3, k = (t & 7) ^ (row & 7);       // A chunk id = t (reg-staged)
        aoff = (m0 + row) * DQ + k * 8;
    }
    int boffs[3];
#pragma unroll
    for (int u = 0; u < 3; ++u) {
        int c = (u * 8 + w) * 64 + lane;                 // B 16B-unit id 0..1535
        int row = c >> 3, k = (c & 7) ^ (row & 7);
        boffs[u] = (n0 + row) * DQ + k * 8;
    }

    f32x4 acc[2][3];
#pragma unroll
    for (int i = 0; i < 2; ++i)
#pragma unroll
        for (int j = 0; j < 3; ++j) acc[i][j] = (f32x4){0.f, 0.f, 0.f, 0.f};

    // ---- prologue: stage kt=0 into buffer 0 ----
    if (MODE == 0) {
        gld16(&Abf[aoff], &smem[w * 512]);
    } else {
        float4 lo = *(const float4*)&Axf[aoff];
        float4 hi = *(const float4*)&Axf[aoff + 4];
        *(uint4v*)&smem[t * 8] =
            (uint4v){pk2(lo.x, lo.y), pk2(lo.z, lo.w), pk2(hi.x, hi.y), pk2(hi.z, hi.w)};
    }
#pragma unroll
    for (int u = 0; u < 3; ++u) gld16(&Wb[boffs[u]], &smem[8192 + (u * 8 + w) * 512]);
    __syncthreads();

    int cur = 0;
    for (int kt = 0; kt < 12; ++kt) {
        float4 fa0, fa1;
        if (kt < 11) {                                   // issue next-tile loads first
            const int k0 = (kt + 1) * 64;
            if (MODE == 0) {
                gld16(&Abf[aoff + k0], &smem[(cur ^ 1) * 4096 + w * 512]);
            } else {
                fa0 = *(const float4*)&Axf[aoff + k0];
                fa1 = *(const float4*)&Axf[aoff + k0 + 4];
            }
#pragma unroll
            for (int u = 0; u < 3; ++u)
                gld16(&Wb[boffs[u] + k0], &smem[8192 + (cur ^ 1) * 12288 + (u * 8 + w) * 512]);
        }
        const short* Asb = &smem[cur * 4096];
        const short* Bsb = &smem[8192 + cur * 12288];
#pragma unroll
        for (int s = 0; s < 2; ++s) {
            const int cq = ((4 * s + qd) ^ (lr & 7)) * 8;    // un-swizzle chunk position
            short8 af[2], bf[3];
#pragma unroll
            for (int i = 0; i < 2; ++i)
                af[i] = *(const short8*)&Asb[(wm + 16 * i + lr) * 64 + cq];
#pragma unroll
            for (int j = 0; j < 3; ++j)
                bf[j] = *(const short8*)&Bsb[(wn + 16 * j + lr) * 64 + cq];
#pragma unroll
            for (int i = 0; i < 2; ++i)
#pragma unroll
                for (int j = 0; j < 3; ++j)
                    acc[i][j] = mfma16(af[i], bf[j], acc[i][j]);
        }
        if (MODE == 1 && kt < 11) {                      // cvt+write into the OTHER buffer
            *(uint4v*)&smem[(cur ^ 1) * 4096 + t * 8] =
                (uint4v){pk2(fa0.x, fa0.y), pk2(fa0.z, fa0.w), pk2(fa1.x, fa1.y), pk2(fa1.z, fa1.w)};
        }
        __syncthreads();                                 // drains DMA + ds_write + read-sync
        cur ^= 1;
    }

    if (MODE == 0) {
#pragma unroll
        for (int i = 0; i < 2; ++i)
#pragma unroll
            for (int j = 0; j < 3; ++j) {
                const int row0 = m0 + wm + 16 * i + qd * 4;
                const int col = n0 + wn + 16 * j + lr;
#pragma unroll
                for (int r = 0; r < 4; ++r)
                    ((float*)Cp)[(size_t)(row0 + r) * DQ + col] = acc[i][j][r];
            }
    } else {
        // block tile = keys kl0..kl0+63 (ONE 64-key fragment tile) of 3 heads
        // {nt*3, +1, +2} of batch m0>>12. F = [3 heads][4096 shorts].
        short* Qf = (short*)Cp;
        short* F = smem;                                 // 12288-short scratch
        const int bh0 = (m0 >> 12) * NH + nt * 3;
        const size_t tilebase = (size_t)(((m0 & 4095) >> 6) << 12);
        // ---- Vf staging (unscaled): packed b64 scatter ----
#pragma unroll
        for (int i = 0; i < 2; ++i)
#pragma unroll
            for (int j = 0; j < 3; ++j) {
                const int kl = wm + 16 * i + qd * 4;     // key 0..63 (4 consecutive)
                const int hsg = wn + 16 * j + lr;        // global d 0..191
                const int hh = hsg >> 6, hs = hsg & 63;
                const int fi = hh * 4096 + ((((hs >> 4) << 1) + ((kl >> 5) & 1)) << 9)
                             + (((hs & 15) + (((kl >> 3) & 3) << 4)) << 3) + (kl & 7);
                *(uint2v*)&F[fi] = (uint2v){pk2(acc[i][j][0], acc[i][j][1]),
                                            pk2(acc[i][j][2], acc[i][j][3])};
            }
        __syncthreads();
#pragma unroll
        for (int p = 0; p < 3; ++p) {
            int u = t + 512 * p;                         // atom id 0..1535
            int hh = u >> 9, rem = u & 511;
            size_t g = (size_t)(bh0 + hh) * (LQ * 64) + tilebase;
            *(short8*)&Vf[g + (size_t)rem * 8] = *(short8*)&F[u * 8];
        }
        __syncthreads();
        // ---- Qf staging (scaled by SQRT_C): b16 scatter ----
#pragma unroll
        for (int i = 0; i < 2; ++i)
#pragma unroll
            for (int j = 0; j < 3; ++j) {
                const int hsg = wn + 16 * j + lr;
                const int hh = hsg >> 6, hs = hsg & 63;
#pragma unroll
                for (int r = 0; r < 4; ++r) {
                    const int key = wm + 16 * i + qd * 4 + r;
                    const int fi = hh * 4096 + (((((key >> 4) & 3) << 1) + (hs >> 5)) << 9)
                                 + (((qd * 4 + r) + (((hs >> 3) & 3) << 4)) << 3) + (hs & 7);
                    F[fi] = f2bf(acc[i][j][r] * SQRT_C);
                }
            }
        __syncthreads();
#pragma unroll
        for (int p = 0; p < 3; ++p) {
            int u = t + 512 * p;
            int hh = u >> 9, rem = u & 511;
            size_t g = (size_t)(bh0 + hh) * (LQ * 64) + tilebase;
            *(short8*)&Qf[g + (size_t)rem * 8] = *(short8*)&F[u * 8];
        }
    }
}

// Split-K-in-block flash attention, K=V=Q, shift-0 softmax, fragment-major loads.
// ROUND-7 OCCUPANCY RESTRUCTURE: block = 4 waves = {1 q-group of 64q} x {4 K-quarters
// of 1024k}; all 4 waves share ONE 64q Q-tile in LDS. Grid = 64 qt x 24 bh = 1536
// blocks = exactly 6/CU; LDS trimmed to 26624B (Ps stride 40->36, conflict-improved)
// so 6 blocks fit 160KB -> 24 waves/CU (was 12). Round-2's 6->12-wave jump gave -26us;
// this doubles TLP again on the same latency-bound profile (MfmaUtil 40, VALU 50).
// Loop body is the PROVEN round-2/4 phase-separated chain, untouched except Ps stride
// and 32 (not 64) kb iterations per wave.
// Shift-0 softmax => partials over disjoint key ranges combine by pure addition:
// 4-round slice-major fp32 LDS exchange (15360B, lane-consecutive = conflict-free),
// wave 0 reduces + normalizes + stores.
__global__ __launch_bounds__(256, 6) void attn(const short* __restrict__ Qf,
                                               const short* __restrict__ Vf,
                                               short* __restrict__ O) {
    const int linear = blockIdx.x;
    const int xcd = linear & 7, slot = linear >> 3;        // 1536 blocks, 8 XCDs
    const int bh = 3 * xcd + (slot >> 6);                  // 3 bh per XCD (L2-resident)
    const int qt = slot & 63;                              // 64 q-tiles of 64
    const int t = threadIdx.x;
    const int lane = t & 63, w = t >> 6;                   // wave = K-quarter, w in {0..3}
    const int lr = lane & 15, qd = lane >> 4;

    // LDS: aqs[4096] shorts (8192B) + Ps [4 w][4 chains][16*36] shorts (18432B)
    // = 26624B; aliased with the 15360B fp32 exchange buffer used after the loop.
    __shared__ alignas(16) short smem[13312];
    short* aqs = smem;                                     // shared 64q Q fragments
    short* Ps = smem + 4096 + w * 2304;                    // per-wave P scratch

    const short* Qbh = Qf + (size_t)bh * (LQ * 64);
    const short* Vbh = Vf + (size_t)bh * (LQ * 64);
    const int q0 = qt * 64;
    const int kb0 = w * 32;                                // 32-key tiles per quarter

    const short one_bf = (short)0x3F80;                    // bf16 1.0
    short8 ones;
#pragma unroll
    for (int j = 0; j < 8; ++j) ones[j] = one_bf;

    // ---- stage this block's 64q Q-fragments into LDS (linear copy, 4096 shorts) ----
#pragma unroll
    for (int p = 0; p < 2; ++p) {
        int off = (t + 256 * p) * 8;
        *(short8*)&aqs[off] = *(const short8*)&Qbh[(size_t)qt * 4096 + off];
    }
    __syncthreads();

    f32x4 oacc[4][4], lacc[4];
#pragma unroll
    for (int i = 0; i < 4; ++i) {
        lacc[i] = (f32x4){0.f, 0.f, 0.f, 0.f};
#pragma unroll
        for (int t2 = 0; t2 < 4; ++t2) oacc[i][t2] = (f32x4){0.f, 0.f, 0.f, 0.f};
    }

    const int aqbase = lane * 8;                           // LDS index of this lane's aq

    for (int kb = kb0; kb < kb0 + 32; ++kb) {
        // ---- phase 1: K frags (32 keys) live; all 4 chains QK -> exp2 -> Ps ----
        short8 kf[2][2];
#pragma unroll
        for (int t4 = 0; t4 < 2; ++t4)
#pragma unroll
            for (int s = 0; s < 2; ++s)
                kf[t4][s] = *(const short8*)&Qbh[kb * 2048 + (t4 * 2 + s) * 512 + lane * 8];

#pragma unroll
        for (int i = 0; i < 4; ++i) {
            short8 aq0 = *(const short8*)&aqs[aqbase + i * 1024];
            short8 aq1 = *(const short8*)&aqs[aqbase + i * 1024 + 512];
            f32x4 s0 = (f32x4){0.f, 0.f, 0.f, 0.f};
            f32x4 s1 = (f32x4){0.f, 0.f, 0.f, 0.f};
            s0 = mfma16(kf[0][0], aq0, s0);
            s0 = mfma16(kf[0][1], aq1, s0);
            s1 = mfma16(kf[1][0], aq0, s1);
            s1 = mfma16(kf[1][1], aq1, s1);
            // lane holds S^T[key=16*t4+qd*4+r][q=lr], already in exp2 domain
            *(uint2v*)&Ps[i * 576 + lr * 36 + 4 * qd] =
                (uint2v){pk2(__builtin_amdgcn_exp2f(s0[0]), __builtin_amdgcn_exp2f(s0[1])),
                         pk2(__builtin_amdgcn_exp2f(s0[2]), __builtin_amdgcn_exp2f(s0[3]))};
            *(uint2v*)&Ps[i * 576 + lr * 36 + 16 + 4 * qd] =
                (uint2v){pk2(__builtin_amdgcn_exp2f(s1[0]), __builtin_amdgcn_exp2f(s1[1])),
                         pk2(__builtin_amdgcn_exp2f(s1[2]), __builtin_amdgcn_exp2f(s1[3]))};
        }

        // ---- phase 2: kf dead; V^T frags (32 keys) live; all 4 chains PV + l ----
        short8 vb[4];
#pragma unroll
        for (int t2 = 0; t2 < 4; ++t2)
            vb[t2] = *(const short8*)&Vbh[(kb >> 1) * 4096 + (kb & 1) * 512 + t2 * 1024 + lane * 8];

#pragma unroll
        for (int i = 0; i < 4; ++i) {
            short8 pa = *(short8*)&Ps[i * 576 + lr * 36 + qd * 8];
#pragma unroll
            for (int t2 = 0; t2 < 4; ++t2)
                oacc[i][t2] = mfma16(pa, vb[t2], oacc[i][t2]);
            lacc[i] = mfma16(pa, ones, lacc[i]);           // row-sum on the MFMA pipe
        }
    }

    // ---- 4-quarter combine: waves 1..3 publish, wave 0 reduces; 4 rounds x 5 slices
    // of f32x4 per lane. Slice-major: buf[slice*64+lane] -> lane-consecutive 16B,
    // conflict-free. Aliases aqs/Ps (dead; barrier-protected). ----
    __syncthreads();
    f32x4* buf = (f32x4*)smem;
#define EXSLOT(idx) ((idx) < 16 ? oacc[(idx) >> 2][(idx) & 3] : lacc[(idx) - 16])
#pragma unroll
    for (int r = 0; r < 4; ++r) {
        if (w) {
#pragma unroll
            for (int s = 0; s < 5; ++s)
                buf[((w - 1) * 5 + s) * 64 + lane] = EXSLOT(r * 5 + s);
        }
        __syncthreads();
        if (w == 0) {
#pragma unroll
            for (int s = 0; s < 5; ++s) {
                f32x4 v = buf[s * 64 + lane];
                v += buf[(5 + s) * 64 + lane];
                v += buf[(10 + s) * 64 + lane];
                EXSLOT(r * 5 + s) += v;
            }
        }
        __syncthreads();
    }
#undef EXSLOT
    if (w) return;

    // l for query qd*4+r is lacc[i][r] in every lane; normalize; store O[b][l][h*64+e]
    const int b = bh / NH, h = bh % NH;
#pragma unroll
    for (int i = 0; i < 4; ++i) {
        float inv[4];
#pragma unroll
        for (int r = 0; r < 4; ++r) inv[r] = 1.0f / lacc[i][r];
#pragma unroll
        for (int t2 = 0; t2 < 4; ++t2)
#pragma unroll
            for (int r = 0; r < 4; ++r) {
                int lq = q0 + 16 * i + qd * 4 + r;
                int e = h * 64 + 16 * t2 + lr;
                O[((size_t)(b * LQ + lq)) * DQ + e] = f2bf(oacc[i][t2][r] * inv[r]);
            }
    }
}

extern "C" void kernel_launch(void* const* d_in, const int* in_sizes, int n_in,
                              void* d_out, int out_size, void* d_ws, size_t ws_size,
                              hipStream_t stream) {
    (void)in_sizes; (void)n_in; (void)out_size; (void)ws_size;
    const float* x  = (const float*)d_in[0];   // fp32 [2,4096,768]
    const float* Wq = (const float*)d_in[1];   // fp32 [768,768]
    const float* Wo = (const float*)d_in[2];   // fp32 [768,768]
    float* out = (float*)d_out;                // fp32 [2,4096,768]

    const size_t NQ = (size_t)NB * NH * LQ * 64;         // 6,291,456 elements
    const size_t NW = (size_t)DQ * DQ;                   // 589,824 elements
    short* Qf  = (short*)d_ws;                           // fragment-major scaled Q
    short* Vfb = Qf + NQ;                                // fragment-major unscaled Q (V)
    short* Ows = Vfb + NQ;                               // attention out (bf16)
    short* Wqb = Ows + (size_t)NB * LQ * DQ;             // bf16 Wq
    short* Wob = Wqb + NW;                               // bf16 Wo

    // 0) Wq/Wo -> bf16 once (enables all-DMA B staging in both gemms)
    cvtw<<<NW / 1024, 256, 0, stream>>>(Wq, Wqb);
    cvtw<<<NW / 1024, 256, 0, stream>>>(Wo, Wob);
    // 1) Q-projection from fp32 x (cvt fused into A staging) -> Qf (scaled) + Vf
    gemm_nt<1><<<512, 512, 0, stream>>>(nullptr, x, Wqb, Qf, Vfb);
    // 2) 4-quarter split-K flash attention (K=V=Q), 24 waves/CU -> Ows
    attn<<<1536, 256, 0, stream>>>(Qf, Vfb, Ows);
    // 3) out = O @ Wo^T, fp32 store
    gemm_nt<0><<<512, 512, 0, stream>>>(Ows, nullptr, Wob, out, nullptr);
}

// Round 8
// 227.856 us; speedup vs baseline: 4.4513x; 4.4513x over previous
//
#include <hip/hip_runtime.h>
#include <hip/hip_bf16.h>

// B=2, L=4096, D=768, H=12, HS=64, SCALE=0.125. Inputs/outputs fp32; bf16 MFMA inside.
#define LQ 4096
#define DQ 768
#define NH 12
#define NB 2

typedef __attribute__((ext_vector_type(8))) short short8;
typedef __attribute__((ext_vector_type(2))) unsigned uint2v;
typedef __attribute__((ext_vector_type(4))) float f32x4;

__device__ __forceinline__ short f2bf(float f) {
    union { float f; unsigned u; } v; v.f = f;
    unsigned r = v.u + 0x7FFFu + ((v.u >> 16) & 1u);   // RNE
    return (short)(r >> 16);
}

__device__ __forceinline__ unsigned pk2(float a, float b) {
    float2 t; t.x = a; t.y = b;
    __hip_bfloat162 h = __float22bfloat162_rn(t);
    unsigned u; __builtin_memcpy(&u, &h, 4);
    return u;
}

__device__ __forceinline__ f32x4 mfma16(short8 a, short8 b, f32x4 c) {
    return __builtin_amdgcn_mfma_f32_16x16x32_bf16(a, b, c, 0, 0, 0);
}

// async 16B global->LDS DMA (dest = wave-uniform base + lane*16)
__device__ __forceinline__ void gld16(const short* g, short* l) {
    __builtin_amdgcn_global_load_lds(
        (const __attribute__((address_space(1))) unsigned int*)(g),
        (__attribute__((address_space(3))) unsigned int*)(l), 16, 0, 0);
}

// sqrt(0.125 * log2(e)): Qf pre-scaled so S^T = (Q')(Q')^T is directly in exp2 domain
#define SQRT_C 0.424660891f

// fp32 -> bf16 bulk convert, n multiple of 1024
__global__ __launch_bounds__(256) void cvtw(const float* __restrict__ a,
                                            short* __restrict__ o) {
    int i = blockIdx.x * 256 + threadIdx.x;
    float4 v = ((const float4*)a)[i];
    *(uint2v*)&o[i * 4] = (uint2v){pk2(v.x, v.y), pk2(v.z, v.w)};
}

// Fragment-major layouts (per bh, per 64-key tile = 4096 shorts, 8 chunks of 512):
//  Qf chunk(t4,s): lane L holds Q[key=16*t4+(L&15)][d=32*s+8*(L>>4)+j]  (SCALED by SQRT_C)
//  Vf chunk(t2,ks): lane L holds Q[key=32*ks+8*(L>>4)+j][d=16*t2+(L&15)] (unscaled)
// Chunk layout is LINEAR in key: 32-key sub-tile kb reads Qf at kb*2048 + (t4*2+s)*512.

// C[M,N] = A[M,K] @ Wb[N,K]^T, M=8192, N=768, K=768. A and Wb both bf16 (pre-cvt).
// ROUND-8: exact round-5 configuration (best measured total). BM=128, BN=192, BK=64,
// 512 threads = 8 waves (2m x 4n) of 64x48 out (acc[4][3]), 256 blocks = 1/CU,
// XCD-affine mt. LDS 80KB double-buffered, gld16 DMA staging, G21 XOR swizzle
// (source chunk k ^ (row&7), linear LDS write, reads un-swizzle), 1 barrier/kt
// (= T3-minimum: stage issued a full compute-phase before its drain).
// MODE 0: C fp32 row-major. MODE 1: BN=192 = 3 heads -> per-head F slabs (verified).
template <int MODE>
__global__ __launch_bounds__(512, 2) void gemm_nt(const short* __restrict__ A,
                                                  const short* __restrict__ Wb,
                                                  void* __restrict__ Cp,
                                                  short* __restrict__ Vf) {
    // carve: As[2][8192] = smem[0..16384), Bs[2][12288] = smem[16384..40960)
    __shared__ __attribute__((aligned(16))) short smem[40960];   // 80 KB
    const int t = threadIdx.x;
    const int lane = t & 63, w = t >> 6;                 // 8 waves
    const int lr = lane & 15, qd = lane >> 4;
    const int wm = (w >> 2) * 64, wn = (w & 3) * 48;     // wave tile 64m x 48n
    const int lin = blockIdx.x;
    const int xcd = lin & 7, jj = lin >> 3;              // 256 blocks, 8 XCDs
    const int nt = jj & 3, mt = (jj >> 2) * 8 + xcd;     // 4 n-tiles x 64 m-tiles
    const int m0 = mt * 128, n0 = nt * 192;

    // kt-invariant per-lane source offsets (XOR-swizzled chunk within each 8-chunk row)
    int aoffs[2], boffs[3];
#pragma unroll
    for (int u = 0; u < 2; ++u) {
        int c = (u * 8 + w) * 64 + lane;                 // A 16B-unit id 0..1023
        int row = c >> 3, k = (c & 7) ^ (row & 7);
        aoffs[u] = (m0 + row) * DQ + k * 8;
    }
#pragma unroll
    for (int u = 0; u < 3; ++u) {
        int c = (u * 8 + w) * 64 + lane;                 // B 16B-unit id 0..1535
        int row = c >> 3, k = (c & 7) ^ (row & 7);
        boffs[u] = (n0 + row) * DQ + k * 8;
    }

    f32x4 acc[4][3];
#pragma unroll
    for (int i = 0; i < 4; ++i)
#pragma unroll
        for (int j = 0; j < 3; ++j) acc[i][j] = (f32x4){0.f, 0.f, 0.f, 0.f};

    // prologue: stage kt=0 into buffer 0
#pragma unroll
    for (int u = 0; u < 2; ++u) gld16(&A[aoffs[u]], &smem[(u * 8 + w) * 512]);
#pragma unroll
    for (int u = 0; u < 3; ++u) gld16(&Wb[boffs[u]], &smem[16384 + (u * 8 + w) * 512]);
    __syncthreads();

    int cur = 0;
    for (int kt = 0; kt < 12; ++kt) {
        if (kt < 11) {                                   // issue next-tile DMA first
            const int k0 = (kt + 1) * 64;
#pragma unroll
            for (int u = 0; u < 2; ++u)
                gld16(&A[aoffs[u] + k0], &smem[(cur ^ 1) * 8192 + (u * 8 + w) * 512]);
#pragma unroll
            for (int u = 0; u < 3; ++u)
                gld16(&Wb[boffs[u] + k0], &smem[16384 + (cur ^ 1) * 12288 + (u * 8 + w) * 512]);
        }
        const short* Asb = &smem[cur * 8192];
        const short* Bsb = &smem[16384 + cur * 12288];
#pragma unroll
        for (int s = 0; s < 2; ++s) {
            const int cq = ((4 * s + qd) ^ (lr & 7)) * 8;    // un-swizzle chunk position
            short8 af[4], bf[3];
#pragma unroll
            for (int i = 0; i < 4; ++i)
                af[i] = *(const short8*)&Asb[(wm + 16 * i + lr) * 64 + cq];
#pragma unroll
            for (int j = 0; j < 3; ++j)
                bf[j] = *(const short8*)&Bsb[(wn + 16 * j + lr) * 64 + cq];
#pragma unroll
            for (int i = 0; i < 4; ++i)
#pragma unroll
                for (int j = 0; j < 3; ++j)
                    acc[i][j] = mfma16(af[i], bf[j], acc[i][j]);
        }
        __syncthreads();                                 // drains DMA (vmcnt) + read-sync
        cur ^= 1;
    }

    if (MODE == 0) {
#pragma unroll
        for (int i = 0; i < 4; ++i)
#pragma unroll
            for (int j = 0; j < 3; ++j) {
                const int row0 = m0 + wm + 16 * i + qd * 4;
                const int col = n0 + wn + 16 * j + lr;
#pragma unroll
                for (int r = 0; r < 4; ++r)
                    ((float*)Cp)[(size_t)(row0 + r) * DQ + col] = acc[i][j][r];
            }
    } else {
        // block tile = keys kl0..kl0+127 of 3 heads {nt*3, +1, +2} of batch m0>>12.
        short* Qf = (short*)Cp;
        short* F = smem;                                 // 24576-short scratch [3][8192]
        const int bh0 = (m0 >> 12) * NH + nt * 3;
        const int kl0 = m0 & 4095;
        // ---- Vf staging (unscaled): packed b64 scatter ----
#pragma unroll
        for (int i = 0; i < 4; ++i)
#pragma unroll
            for (int j = 0; j < 3; ++j) {
                const int kl = wm + 16 * i + qd * 4;     // key 0..127 (4 consecutive)
                const int hsg = wn + 16 * j + lr;        // global d 0..191
                const int hh = hsg >> 6, hs = hsg & 63;
                const int fi = hh * 8192 + ((kl >> 6) & 1) * 4096
                             + ((((hs >> 4) << 1) + ((kl >> 5) & 1)) << 9)
                             + (((hs & 15) + (((kl >> 3) & 3) << 4)) << 3) + (kl & 7);
                *(uint2v*)&F[fi] = (uint2v){pk2(acc[i][j][0], acc[i][j][1]),
                                            pk2(acc[i][j][2], acc[i][j][3])};
            }
        __syncthreads();
#pragma unroll
        for (int p = 0; p < 6; ++p) {
            int u = t + 512 * p;                         // atom id 0..3071
            int hh = u >> 10, rem = u & 1023;
            size_t g = (size_t)(bh0 + hh) * (LQ * 64) + (size_t)((kl0 >> 6) << 12);
            *(short8*)&Vf[g + (size_t)rem * 8] = *(short8*)&F[u * 8];
        }
        __syncthreads();
        // ---- Qf staging (scaled by SQRT_C): b16 scatter ----
#pragma unroll
        for (int i = 0; i < 4; ++i)
#pragma unroll
            for (int j = 0; j < 3; ++j) {
                const int hsg = wn + 16 * j + lr;
                const int hh = hsg >> 6, hs = hsg & 63;
#pragma unroll
                for (int r = 0; r < 4; ++r) {
                    const int key = wm + 16 * i + qd * 4 + r;
                    const int fi = hh * 8192 + ((key >> 6) & 1) * 4096
                                 + (((((key >> 4) & 3) << 1) + (hs >> 5)) << 9)
                                 + (((qd * 4 + r) + (((hs >> 3) & 3) << 4)) << 3) + (hs & 7);
                    F[fi] = f2bf(acc[i][j][r] * SQRT_C);
                }
            }
        __syncthreads();
#pragma unroll
        for (int p = 0; p < 6; ++p) {
            int u = t + 512 * p;
            int hh = u >> 10, rem = u & 1023;
            size_t g = (size_t)(bh0 + hh) * (LQ * 64) + (size_t)((kl0 >> 6) << 12);
            *(short8*)&Qf[g + (size_t)rem * 8] = *(short8*)&F[u * 8];
        }
    }
}

// Split-K-in-block flash attention, K=V=Q, shift-0 softmax, fragment-major loads.
// EXACT round-2/4 proven structure (129.4us): 4-wave (256t) blocks = {2 q-groups of
// 64q} x {2 key-halves of 2048k}; 768 blocks = 3/CU = 12 waves/CU; (256,3) = ~170
// unified regs/wave. ROUND-7 LESSON (2nd offense): the loop's live set is ~150 unified
// regs (76 arch-VGPR + 80-f32 acc) -- ANY cap below ~170 spills catastrophically.
// 12 waves/CU is this structure's occupancy ceiling. Counters show MfmaUtil 40 +
// VALUBusy 50 = ~90% combined issue => near issue-bound; this round adds T5
// s_setprio(1) around the MFMA clusters (m191: +4-7% on attn with independent wave
// phases; our loop has no barriers -> waves drift apart -> T5's regime).
__global__ __launch_bounds__(256, 3) void attn(const short* __restrict__ Qf,
                                               const short* __restrict__ Vf,
                                               short* __restrict__ O) {
    const int linear = blockIdx.x;
    const int xcd = linear & 7, slot = linear >> 3;        // 768 blocks, 8 XCDs
    const int bh = 3 * xcd + (slot >> 5);                  // 3 bh per XCD (L2-resident)
    const int qtile = slot & 31;                           // 32 q-tiles of 128
    const int t = threadIdx.x;
    const int lane = t & 63, w = t >> 6;                   // w in {0..3}
    const int qw = w & 1, half = w >> 1;                   // q-group, key-half
    const int lr = lane & 15, qd = lane >> 4;

    // LDS: aqs [2 qw][4096] shorts (16384B) + Ps [4 w][4 chains][16*40] shorts (20480B)
    // = 36864B, all aliased with the 43008B fp32 exchange buffer used after the loop.
    __shared__ alignas(16) char smem[43008];
    short* aqs = (short*)smem;                             // Q fragments, per q-group
    short* Ps = (short*)(smem + 16384) + w * 2560;         // per-wave P scratch (shorts)

    const short* Qbh = Qf + (size_t)bh * (LQ * 64);
    const short* Vbh = Vf + (size_t)bh * (LQ * 64);
    const int q0 = qtile * 128 + qw * 64;
    const int kb0 = half * 64;                             // 32-key tiles: 0..63 / 64..127

    const short one_bf = (short)0x3F80;                    // bf16 1.0
    short8 ones;
#pragma unroll
    for (int j = 0; j < 8; ++j) ones[j] = one_bf;

    // ---- stage this block's 128q Q-fragments into LDS (both q-groups, linear copy) ----
#pragma unroll
    for (int p = 0; p < 4; ++p) {
        int off = (t + 256 * p) * 8;                       // 0..8191 shorts
        *(short8*)&aqs[off] = *(const short8*)&Qbh[(size_t)qtile * 8192 + off];
    }
    __syncthreads();

    f32x4 oacc[4][4], lacc[4];
#pragma unroll
    for (int i = 0; i < 4; ++i) {
        lacc[i] = (f32x4){0.f, 0.f, 0.f, 0.f};
#pragma unroll
        for (int t2 = 0; t2 < 4; ++t2) oacc[i][t2] = (f32x4){0.f, 0.f, 0.f, 0.f};
    }

    const int aqbase = qw * 4096 + lane * 8;               // LDS index of this lane's aq

    for (int kb = kb0; kb < kb0 + 64; ++kb) {
        // ---- phase 1: K frags (32 keys) live; all 4 chains QK -> exp2 -> Ps ----
        short8 kf[2][2];
#pragma unroll
        for (int t4 = 0; t4 < 2; ++t4)
#pragma unroll
            for (int s = 0; s < 2; ++s)
                kf[t4][s] = *(const short8*)&Qbh[kb * 2048 + (t4 * 2 + s) * 512 + lane * 8];

#pragma unroll
        for (int i = 0; i < 4; ++i) {
            short8 aq0 = *(const short8*)&aqs[aqbase + i * 1024];
            short8 aq1 = *(const short8*)&aqs[aqbase + i * 1024 + 512];
            f32x4 s0 = (f32x4){0.f, 0.f, 0.f, 0.f};
            f32x4 s1 = (f32x4){0.f, 0.f, 0.f, 0.f};
            __builtin_amdgcn_s_setprio(1);                 // T5: favor MFMA cluster
            s0 = mfma16(kf[0][0], aq0, s0);
            s0 = mfma16(kf[0][1], aq1, s0);
            s1 = mfma16(kf[1][0], aq0, s1);
            s1 = mfma16(kf[1][1], aq1, s1);
            __builtin_amdgcn_s_setprio(0);
            // lane holds S^T[key=16*t4+qd*4+r][q=lr], already in exp2 domain
            *(uint2v*)&Ps[i * 640 + lr * 40 + 4 * qd] =
                (uint2v){pk2(__builtin_amdgcn_exp2f(s0[0]), __builtin_amdgcn_exp2f(s0[1])),
                         pk2(__builtin_amdgcn_exp2f(s0[2]), __builtin_amdgcn_exp2f(s0[3]))};
            *(uint2v*)&Ps[i * 640 + lr * 40 + 16 + 4 * qd] =
                (uint2v){pk2(__builtin_amdgcn_exp2f(s1[0]), __builtin_amdgcn_exp2f(s1[1])),
                         pk2(__builtin_amdgcn_exp2f(s1[2]), __builtin_amdgcn_exp2f(s1[3]))};
        }

        // ---- phase 2: kf dead; V^T frags (32 keys) live; all 4 chains PV + l ----
        short8 vb[4];
#pragma unroll
        for (int t2 = 0; t2 < 4; ++t2)
            vb[t2] = *(const short8*)&Vbh[(kb >> 1) * 4096 + (kb & 1) * 512 + t2 * 1024 + lane * 8];

        __builtin_amdgcn_s_setprio(1);                     // T5: PV is MFMA-dominated
#pragma unroll
        for (int i = 0; i < 4; ++i) {
            short8 pa = *(short8*)&Ps[i * 640 + lr * 40 + qd * 8];
#pragma unroll
            for (int t2 = 0; t2 < 4; ++t2)
                oacc[i][t2] = mfma16(pa, vb[t2], oacc[i][t2]);
            lacc[i] = mfma16(pa, ones, lacc[i]);           // row-sum on the MFMA pipe
        }
        __builtin_amdgcn_s_setprio(0);
    }

    // ---- split-K combine: half=1 waves publish fp32 partials, half=0 waves reduce ----
    __syncthreads();                                       // Ps/aqs dead from here; alias ok
    f32x4* ex = (f32x4*)smem + (qw * 64 + lane) * 21;      // stride 21: bank-conflict-free
    if (half) {
#pragma unroll
        for (int i = 0; i < 4; ++i) {
#pragma unroll
            for (int t2 = 0; t2 < 4; ++t2) ex[i * 4 + t2] = oacc[i][t2];
            ex[16 + i] = lacc[i];
        }
    }
    __syncthreads();
    if (half) return;

#pragma unroll
    for (int i = 0; i < 4; ++i) {
#pragma unroll
        for (int t2 = 0; t2 < 4; ++t2) oacc[i][t2] += ex[i * 4 + t2];
        lacc[i] += ex[16 + i];
    }

    // l for query qd*4+r is lacc[i][r] in every lane; normalize; store O[b][l][h*64+e]
    const int b = bh / NH, h = bh % NH;
#pragma unroll
    for (int i = 0; i < 4; ++i) {
        float inv[4];
#pragma unroll
        for (int r = 0; r < 4; ++r) inv[r] = 1.0f / lacc[i][r];
#pragma unroll
        for (int t2 = 0; t2 < 4; ++t2)
#pragma unroll
            for (int r = 0; r < 4; ++r) {
                int lq = q0 + 16 * i + qd * 4 + r;
                int e = h * 64 + 16 * t2 + lr;
                O[((size_t)(b * LQ + lq)) * DQ + e] = f2bf(oacc[i][t2][r] * inv[r]);
            }
    }
}

extern "C" void kernel_launch(void* const* d_in, const int* in_sizes, int n_in,
                              void* d_out, int out_size, void* d_ws, size_t ws_size,
                              hipStream_t stream) {
    (void)in_sizes; (void)n_in; (void)out_size; (void)ws_size;
    const float* x  = (const float*)d_in[0];   // fp32 [2,4096,768]
    const float* Wq = (const float*)d_in[1];   // fp32 [768,768]
    const float* Wo = (const float*)d_in[2];   // fp32 [768,768]
    float* out = (float*)d_out;                // fp32 [2,4096,768]

    const size_t NQ = (size_t)NB * NH * LQ * 64;         // 6,291,456 elements
    const size_t NW = (size_t)DQ * DQ;                   // 589,824 elements
    short* Qf  = (short*)d_ws;                           // fragment-major scaled Q
    short* Vfb = Qf + NQ;                                // fragment-major unscaled Q (V)
    short* Ows = Vfb + NQ;                               // xb, then attention out
    short* Wqb = Ows + (size_t)NB * LQ * DQ;             // bf16 Wq
    short* Wob = Wqb + NW;                               // bf16 Wo

    // 1) x -> bf16 (into Ows slot); Wq/Wo -> bf16 once
    cvtw<<<(NB * LQ * DQ) / 1024, 256, 0, stream>>>(x, Ows);
    cvtw<<<NW / 1024, 256, 0, stream>>>(Wq, Wqb);
    cvtw<<<NW / 1024, 256, 0, stream>>>(Wo, Wob);
    // 2) Q-projection -> fragment-major Qf (scaled) + Vf (fat-tile gemm, 256 blocks)
    gemm_nt<1><<<256, 512, 0, stream>>>(Ows, Wqb, Qf, Vfb);
    // 3) split-K flash attention (K=V=Q), 12 waves/CU, T5 setprio -> Ows
    attn<<<768, 256, 0, stream>>>(Qf, Vfb, Ows);
    // 4) out = O @ bf16(Wo)^T, fp32 store (fat-tile gemm, 256 blocks)
    gemm_nt<0><<<256, 512, 0, stream>>>(Ows, Wob, out, nullptr);
}